// Round 6
// baseline (502.548 us; speedup 1.0000x reference)
//
#include <hip/hip_runtime.h>
#include <math.h>

#define NODES 100000
#define EDGES 1600000
#define HF 128
#define NC 20
#define BSHIFT 9
#define BK 512                          // nodes per bucket
#define NBK ((NODES + BK - 1) / BK)     // 196 buckets
#define EPB 8192                        // edges per partition block
#define NPB ((EDGES + EPB - 1) / EPB)   // 196 blocks

typedef __attribute__((ext_vector_type(8))) short bf16x8;
typedef __attribute__((ext_vector_type(4))) float f32x4;

__device__ __forceinline__ ushort f2b(float f) {
    uint u = __float_as_uint(f);
    uint r = (u + 0x7FFFu + ((u >> 16) & 1u)) >> 16;
    return (ushort)r;
}
__device__ __forceinline__ float b2f(ushort h) { return __uint_as_float(((uint)h) << 16); }

// ---- bucketed counting sort of edges by dst ----

__global__ void bucket_hist(const int* __restrict__ dst, int* __restrict__ btot, int E) {
    __shared__ int h[NBK];
    for (int i = threadIdx.x; i < NBK; i += 256) h[i] = 0;
    __syncthreads();
    int base = blockIdx.x * EPB;
    for (int i = threadIdx.x; i < EPB; i += 256) {
        int e = base + i;
        if (e < E) atomicAdd(&h[dst[e] >> BSHIFT], 1);
    }
    __syncthreads();
    for (int i = threadIdx.x; i < NBK; i += 256)
        if (h[i]) atomicAdd(&btot[i], h[i]);
}

__global__ void bucket_scan(const int* __restrict__ btot, int* __restrict__ boff,
                            int* __restrict__ bcur) {
    __shared__ int p[256];
    int t = threadIdx.x;
    p[t] = (t < NBK) ? btot[t] : 0;
    __syncthreads();
    for (int st = 1; st < 256; st <<= 1) {
        int u = (t >= st) ? p[t - st] : 0;
        __syncthreads();
        p[t] += u;
        __syncthreads();
    }
    int excl = (t == 0) ? 0 : p[t - 1];
    if (t < NBK) { boff[t] = excl; bcur[t] = excl; }
    if (t == NBK - 1) boff[NBK] = p[t];
}

__global__ void partition_kernel(const int* __restrict__ src, const int* __restrict__ dst,
                                 int* __restrict__ bcur, uint2* __restrict__ ebuf, int E) {
    __shared__ int h[NBK];
    __shared__ int basea[NBK];
    for (int i = threadIdx.x; i < NBK; i += 256) h[i] = 0;
    __syncthreads();
    int base = blockIdx.x * EPB;
    for (int i = threadIdx.x; i < EPB; i += 256) {
        int e = base + i;
        if (e < E) atomicAdd(&h[dst[e] >> BSHIFT], 1);
    }
    __syncthreads();
    for (int i = threadIdx.x; i < NBK; i += 256) {
        int c = h[i];
        basea[i] = c ? atomicAdd(&bcur[i], c) : 0;
    }
    __syncthreads();
    for (int i = threadIdx.x; i < NBK; i += 256) h[i] = 0;
    __syncthreads();
    for (int i = threadIdx.x; i < EPB; i += 256) {
        int e = base + i;
        if (e < E) {
            int d = dst[e];
            int b = d >> BSHIFT;
            int pos = basea[b] + atomicAdd(&h[b], 1);
            ebuf[pos] = make_uint2((uint)src[e], (uint)d);
        }
    }
}

__global__ void bucket_sort(const uint2* __restrict__ ebuf, const int* __restrict__ boff,
                            int* __restrict__ off, int* __restrict__ ssrc, int n) {
    __shared__ int deg[BK];
    __shared__ int lcur[BK];
    __shared__ int ps[BK];
    int b = blockIdx.x;
    int t = threadIdx.x;  // 0..511
    int e0 = boff[b], e1 = boff[b + 1];
    int nbase = b << BSHIFT;

    deg[t] = 0;
    __syncthreads();
    for (int e = e0 + t; e < e1; e += BK)
        atomicAdd(&deg[ebuf[e].y & (BK - 1)], 1);
    __syncthreads();
    ps[t] = deg[t];
    __syncthreads();
    for (int st = 1; st < BK; st <<= 1) {
        int u = (t >= st) ? ps[t - st] : 0;
        __syncthreads();
        ps[t] += u;
        __syncthreads();
    }
    int start = e0 + ((t == 0) ? 0 : ps[t - 1]);
    lcur[t] = start;
    int node = nbase + t;
    if (node < n) off[node] = start;
    __syncthreads();
    for (int e = e0 + t; e < e1; e += BK) {
        uint2 ed = ebuf[e];
        int pos = atomicAdd(&lcur[ed.y & (BK - 1)], 1);
        ssrc[pos] = (int)ed.x;
    }
    if (b == 0 && t == 0) off[n] = EDGES;
}

// ---- fp32 -> bf16 converters ----

__global__ void cvt_x_kernel(const float* __restrict__ in, ushort* __restrict__ out, int n8) {
    int i = blockIdx.x * blockDim.x + threadIdx.x;
    if (i >= n8) return;
    const float4* p = (const float4*)in + (size_t)i * 2;
    float4 a = p[0], b = p[1];
    uint4 o;
    o.x = (uint)f2b(a.x) | ((uint)f2b(a.y) << 16);
    o.y = (uint)f2b(a.z) | ((uint)f2b(a.w) << 16);
    o.z = (uint)f2b(b.x) | ((uint)f2b(b.y) << 16);
    o.w = (uint)f2b(b.z) | ((uint)f2b(b.w) << 16);
    ((uint4*)out)[i] = o;
}

__global__ void cvt_weights_kernel(const float* __restrict__ a, const float* __restrict__ b,
                                   const float* __restrict__ c, const float* __restrict__ d,
                                   const float* __restrict__ e, ushort* __restrict__ out) {
    int i = blockIdx.x * blockDim.x + threadIdx.x;  // 0..81919
    const float* srcs[5] = {a, b, c, d, e};
    int seg = i >> 14;
    int off = i & 16383;
    out[i] = f2b(srcs[seg][off]);
}

// ---- mean-aggregate over sorted edge segments ----
// 32 lanes per node; lane = (sel,cl): sel = which edge of a pair, cl = 8-col group.
// Main loop covers 8 edges/iter with 4 x uint4 loads in flight per lane (64 B).
__global__ void aggregate_bf16(const ushort* __restrict__ x, const int* __restrict__ ssrc,
                               const int* __restrict__ off, ushort* __restrict__ agg, int n) {
    int tid = blockIdx.x * blockDim.x + threadIdx.x;
    int node = tid >> 5;
    if (node >= n) return;
    int sub = tid & 31;
    int sel = sub >> 4;           // 0 or 1
    int c8 = (sub & 15) << 3;     // col group * 8
    int s0 = off[node], s1 = off[node + 1];

    float acc[8];
#pragma unroll
    for (int i = 0; i < 8; ++i) acc[i] = 0.f;

    const ushort* xc = x + c8;
    int e = s0;
    for (; e + 7 < s1; e += 8) {
        int sa = ssrc[e + sel];
        int sb = ssrc[e + 2 + sel];
        int sc_ = ssrc[e + 4 + sel];
        int sd = ssrc[e + 6 + sel];
        uint4 va = *(const uint4*)(xc + (size_t)sa * HF);
        uint4 vb = *(const uint4*)(xc + (size_t)sb * HF);
        uint4 vc = *(const uint4*)(xc + (size_t)sc_ * HF);
        uint4 vd = *(const uint4*)(xc + (size_t)sd * HF);
        const uint* pa = (const uint*)&va;
        const uint* pb = (const uint*)&vb;
        const uint* pc = (const uint*)&vc;
        const uint* pd = (const uint*)&vd;
#pragma unroll
        for (int i = 0; i < 4; ++i) {
            acc[2 * i]     += __uint_as_float(pa[i] << 16) + __uint_as_float(pb[i] << 16)
                            + __uint_as_float(pc[i] << 16) + __uint_as_float(pd[i] << 16);
            acc[2 * i + 1] += __uint_as_float(pa[i] & 0xFFFF0000u) + __uint_as_float(pb[i] & 0xFFFF0000u)
                            + __uint_as_float(pc[i] & 0xFFFF0000u) + __uint_as_float(pd[i] & 0xFFFF0000u);
        }
    }
    for (; e < s1; e += 2) {
        if (e + sel < s1) {
            int sa = ssrc[e + sel];
            uint4 va = *(const uint4*)(xc + (size_t)sa * HF);
            const uint* pa = (const uint*)&va;
#pragma unroll
            for (int i = 0; i < 4; ++i) {
                acc[2 * i]     += __uint_as_float(pa[i] << 16);
                acc[2 * i + 1] += __uint_as_float(pa[i] & 0xFFFF0000u);
            }
        }
    }

    // combine the two 16-lane halves
#pragma unroll
    for (int i = 0; i < 8; ++i) acc[i] += __shfl_xor(acc[i], 16);

    if (sel == 0) {
        float invd = 1.0f / fmaxf((float)(s1 - s0), 1.0f);
        uint4 o;
        uint* po = (uint*)&o;
#pragma unroll
        for (int i = 0; i < 4; ++i)
            po[i] = (uint)f2b(acc[2 * i] * invd) | ((uint)f2b(acc[2 * i + 1] * invd) << 16);
        *(uint4*)(agg + (size_t)node * HF + c8) = o;
    }
}

// ---- MFMA linear: out = relu(bias + A1@W1^T (+ A2@W2^T)), bf16 in/out, fp32 accum ----
template<bool DUAL>
__global__ __launch_bounds__(256)
void mfma_linear(const ushort* __restrict__ A1, const ushort* __restrict__ A2,
                 const ushort* __restrict__ W1, const ushort* __restrict__ W2,
                 const float* __restrict__ bias, ushort* __restrict__ out, int n) {
    int wave = threadIdx.x >> 6;
    int lane = threadIdx.x & 63;
    int m = lane & 15, quad = lane >> 4;
    int row0b = blockIdx.x * 64;

    bf16x8 b1[2][4], b2[2][4];
#pragma unroll
    for (int ct = 0; ct < 2; ++ct) {
        int col = wave * 32 + ct * 16 + m;
#pragma unroll
        for (int ks = 0; ks < 4; ++ks) {
            b1[ct][ks] = *(const bf16x8*)(W1 + (size_t)col * HF + ks * 32 + quad * 8);
            if (DUAL) b2[ct][ks] = *(const bf16x8*)(W2 + (size_t)col * HF + ks * 32 + quad * 8);
        }
    }
    float bia0 = bias[wave * 32 + m];
    float bia1 = bias[wave * 32 + 16 + m];

#pragma unroll
    for (int rt = 0; rt < 4; ++rt) {
        int row0 = row0b + rt * 16;
        if (row0 >= n) break;
        f32x4 acc0 = {0.f, 0.f, 0.f, 0.f};
        f32x4 acc1 = {0.f, 0.f, 0.f, 0.f};
        const ushort* arow = A1 + (size_t)(row0 + m) * HF + quad * 8;
#pragma unroll
        for (int ks = 0; ks < 4; ++ks) {
            bf16x8 a = *(const bf16x8*)(arow + ks * 32);
            acc0 = __builtin_amdgcn_mfma_f32_16x16x32_bf16(a, b1[0][ks], acc0, 0, 0, 0);
            acc1 = __builtin_amdgcn_mfma_f32_16x16x32_bf16(a, b1[1][ks], acc1, 0, 0, 0);
        }
        if (DUAL) {
            const ushort* arow2 = A2 + (size_t)(row0 + m) * HF + quad * 8;
#pragma unroll
            for (int ks = 0; ks < 4; ++ks) {
                bf16x8 a = *(const bf16x8*)(arow2 + ks * 32);
                acc0 = __builtin_amdgcn_mfma_f32_16x16x32_bf16(a, b2[0][ks], acc0, 0, 0, 0);
                acc1 = __builtin_amdgcn_mfma_f32_16x16x32_bf16(a, b2[1][ks], acc1, 0, 0, 0);
            }
        }
        // C/D layout: col = lane&15, row = quad*4 + reg
#pragma unroll
        for (int i = 0; i < 4; ++i) {
            size_t r = (size_t)(row0 + quad * 4 + i);
            out[r * HF + wave * 32 + m]      = f2b(fmaxf(acc0[i] + bia0, 0.f));
            out[r * HF + wave * 32 + 16 + m] = f2b(fmaxf(acc1[i] + bia1, 0.f));
        }
    }
}

// out[i][j] = sigmoid(bm2[j] + sum_k A[i][k]*W[j][k]), j < 20. A is bf16.
__global__ void head_kernel(const ushort* __restrict__ A, const float* __restrict__ W,
                            const float* __restrict__ bias, float* __restrict__ out, int n) {
    const int ROWS = 8;
    __shared__ float sA[ROWS * 129];
    __shared__ float sW[NC * 129];
    int row0 = blockIdx.x * ROWS;

    for (int idx = threadIdx.x; idx < NC * HF; idx += blockDim.x) {
        int j = idx >> 7, k = idx & (HF - 1);
        sW[j * 129 + k] = W[idx];
    }
    for (int idx = threadIdx.x; idx < ROWS * HF; idx += blockDim.x) {
        int r = idx >> 7, k = idx & (HF - 1);
        int i = row0 + r;
        sA[r * 129 + k] = (i < n) ? b2f(A[(size_t)i * HF + k]) : 0.f;
    }
    __syncthreads();

    int t = threadIdx.x;
    if (t < ROWS * NC) {
        int r = t / NC, j = t - r * NC;
        int i = row0 + r;
        if (i < n) {
            float acc = bias[j];
#pragma unroll 8
            for (int k = 0; k < HF; ++k)
                acc = fmaf(sA[r * 129 + k], sW[j * 129 + k], acc);
            out[(size_t)i * NC + j] = 1.0f / (1.0f + expf(-acc));
        }
    }
}

extern "C" void kernel_launch(void* const* d_in, const int* in_sizes, int n_in,
                              void* d_out, int out_size, void* d_ws, size_t ws_size,
                              hipStream_t stream) {
    const float* x   = (const float*)d_in[0];
    const int*   ei  = (const int*)d_in[1];
    const float* W1l = (const float*)d_in[2];
    const float* b1  = (const float*)d_in[3];
    const float* W1r = (const float*)d_in[4];
    const float* W2l = (const float*)d_in[5];
    const float* b2  = (const float*)d_in[6];
    const float* W2r = (const float*)d_in[7];
    const float* Wm1 = (const float*)d_in[8];
    const float* bm1 = (const float*)d_in[9];
    const float* Wm2 = (const float*)d_in[10];
    const float* bm2 = (const float*)d_in[11];
    float* out = (float*)d_out;

    const int N = NODES, E = EDGES;
    const int* src = ei;
    const int* dst = ei + E;

    // workspace layout (16B-aligned sections)
    int* boff   = (int*)d_ws;            // 256 (NBK+1 used)
    int* btot   = boff + 256;            // 256
    int* bcur   = btot + 256;            // 256
    int* off    = bcur + 256;            // N+8
    int* ssrc   = off + N + 8;           // E
    ushort* xb   = (ushort*)(ssrc + E);  // N*HF each below
    ushort* aggA = xb + (size_t)N * HF;
    ushort* h1   = aggA + (size_t)N * HF;
    ushort* h2   = h1 + (size_t)N * HF;
    uint2* ebuf  = (uint2*)h2;           // aliases h2 (dead until layer-2 linear)
    ushort* wb   = h2 + (size_t)N * HF;  // 5*16384 bf16 weights
    ushort* wb1l = wb;
    ushort* wb1r = wb + 16384;
    ushort* wb2l = wb + 32768;
    ushort* wb2r = wb + 49152;
    ushort* wbm1 = wb + 65536;

    // ---- bucketed sort of edges by dst ----
    hipMemsetAsync(btot, 0, 256 * sizeof(int), stream);
    bucket_hist<<<NPB, 256, 0, stream>>>(dst, btot, E);
    bucket_scan<<<1, 256, 0, stream>>>(btot, boff, bcur);
    partition_kernel<<<NPB, 256, 0, stream>>>(src, dst, bcur, ebuf, E);
    bucket_sort<<<NBK, BK, 0, stream>>>(ebuf, boff, off, ssrc, N);

    // ---- bf16 conversion ----
    const int n8 = N * HF / 8;
    cvt_x_kernel<<<(n8 + 255) / 256, 256, 0, stream>>>(x, xb, n8);
    cvt_weights_kernel<<<320, 256, 0, stream>>>(W1l, W1r, W2l, W2r, Wm1, wb);

    const int aggBlocks = (N * 32 + 255) / 256;
    const int linBlocks = (N + 63) / 64;

    // ---- layer 1 ----
    aggregate_bf16<<<aggBlocks, 256, 0, stream>>>(xb, ssrc, off, aggA, N);
    mfma_linear<true><<<linBlocks, 256, 0, stream>>>(aggA, xb, wb1l, wb1r, b1, h1, N);

    // ---- layer 2 (agg output reuses xb; ebuf/h2 region now free for h2) ----
    aggregate_bf16<<<aggBlocks, 256, 0, stream>>>(h1, ssrc, off, xb, N);
    mfma_linear<true><<<linBlocks, 256, 0, stream>>>(xb, h1, wb2l, wb2r, b2, h2, N);

    // ---- MLP hidden (out reuses aggA) ----
    mfma_linear<false><<<linBlocks, 256, 0, stream>>>(h2, nullptr, wbm1, nullptr, bm1, aggA, N);

    // ---- head + sigmoid ----
    head_kernel<<<(N + 7) / 8, 256, 0, stream>>>(aggA, Wm2, bm2, out, N);
}